// Round 15
// baseline (523.045 us; speedup 1.0000x reference)
//
#include <hip/hip_runtime.h>
#include <hip/hip_bf16.h>

#define SEQ   101
#define BATCH 16384
#define INP   9
#define HID   32
#define NOUT  3
#define HSlin 3232          // HID*SEQ
#define SB    (SEQ * BATCH) // flattened (s,b) cols

typedef __attribute__((ext_vector_type(8))) _Float16 half8;   // 8 fp16 (4 VGPRs)
typedef __attribute__((ext_vector_type(8))) short short8;
typedef __attribute__((ext_vector_type(4))) float f32x4;      // MFMA C/D
typedef __attribute__((ext_vector_type(2))) float f32x2;      // v_pk_* pairs
typedef __attribute__((ext_vector_type(4))) unsigned u32x4;

#define LOG2E   1.4426950408889634f
#define N2LOG2E (-2.8853900817779268f)

// pack two f32 -> half2 in one v_cvt_pkrtz_f16_f32
__device__ __forceinline__ unsigned pkh(float a, float b) {
    return __builtin_bit_cast(unsigned, __builtin_amdgcn_cvt_pkrtz(a, b));
}
// DPP row_ror:8 — within each 16-lane row, lane i <-> lane i^8
__device__ __forceinline__ unsigned dpp8u(unsigned v) {
    return (unsigned)__builtin_amdgcn_mov_dpp((int)v, 0x128, 0xF, 0xF, true);
}
__device__ __forceinline__ float dpp8f(float v) {
    return __int_as_float(__builtin_amdgcn_mov_dpp(__float_as_int(v), 0x128, 0xF, 0xF, true));
}
// lane i <-> i^4 via ds_swizzle BitMode: offset = (xor=4)<<10 | and=0x1F
__device__ __forceinline__ unsigned swz4u(unsigned v) {
    return (unsigned)__builtin_amdgcn_ds_swizzle((int)v, 0x101F);
}
__device__ __forceinline__ float swz4f(float v) {
    return __int_as_float(__builtin_amdgcn_ds_swizzle(__float_as_int(v), 0x101F));
}

// Swapped-operand fp16 scheme: gates^T = W * [x|1|h]^T  (verified R14 math).
// Weights pre-scaled by log2e (i,f,o) / 2*log2e (g) so activations use raw exp2.
// h k-permutation: pi(8g+j) = 4g + (j&3) + 16*(j>>2).
// x map: k=0..8 -> W_ih col k; k==9 -> combined bias (x supplies 1.0); k>=10 -> 0.
__global__ void prep_kernel(const float* __restrict__ W_ih, const float* __restrict__ W_hh,
                            const float* __restrict__ b_ih, const float* __restrict__ b_hh,
                            unsigned short* __restrict__ whh16, unsigned short* __restrict__ wih16) {
    int tid = threadIdx.x;            // 0..511 : t = tid>>6, l = tid&63
    int l   = tid & 63;
    int t   = tid >> 6;
    int row = l & 15;                 // gate-in-tile
    int g   = l >> 4;
    int gate = 16 * t + row;
    float sc = ((gate >> 5) == 2) ? (2.f * LOG2E) : LOG2E;    // g-gate: tanh needs e^{-2g}
    for (int j = 0; j < 8; ++j) {
        int u = 4 * g + (j & 3) + 16 * (j >> 2);     // pi(8g+j)
        _Float16 wh = (_Float16)(W_hh[gate * HID + u] * sc);
        whh16[tid * 8 + j] = __builtin_bit_cast(unsigned short, wh);
        int k = 8 * g + j;
        float wv;
        if      (k < INP)  wv = W_ih[gate * INP + k] * sc;
        else if (k == INP) wv = (b_ih[gate] + b_hh[gate]) * sc;   // bias slot
        else               wv = 0.f;
        _Float16 wi = (_Float16)wv;
        wih16[tid * 8 + j] = __builtin_bit_cast(unsigned short, wi);
    }
}

// Merged emit for both groups. Inputs: per-lane partials of group A and B.
// Reduce bits 3 (DPP), 4,5 (shfl); pair-merge bit 2 via select+swz4 so that
// lanes 0-7 hold cols b0..b0+7 -> one contiguous 32B store run per plane.
template<bool PLANES>
__device__ __forceinline__ void emit_prev2(float a0, float a1, float a2,
                                           float e0, float e1, float e2,
                                           unsigned psb, float* __restrict__ dataout,
                                           int lane) {
    a0 += dpp8f(a0); a1 += dpp8f(a1); a2 += dpp8f(a2);
    e0 += dpp8f(e0); e1 += dpp8f(e1); e2 += dpp8f(e2);
    a0 += __shfl_xor(a0, 16); a1 += __shfl_xor(a1, 16); a2 += __shfl_xor(a2, 16);
    e0 += __shfl_xor(e0, 16); e1 += __shfl_xor(e1, 16); e2 += __shfl_xor(e2, 16);
    a0 += __shfl_xor(a0, 32); a1 += __shfl_xor(a1, 32); a2 += __shfl_xor(a2, 32);
    e0 += __shfl_xor(e0, 32); e1 += __shfl_xor(e1, 32); e2 += __shfl_xor(e2, 32);
    const bool hi4 = (lane & 4) != 0;
    float q0 = hi4 ? e0 : a0, r0 = hi4 ? a0 : e0;
    float q1 = hi4 ? e1 : a1, r1 = hi4 ? a1 : e1;
    float q2 = hi4 ? e2 : a2, r2 = hi4 ? a2 : e2;
    q0 += swz4f(r0); q1 += swz4f(r1); q2 += swz4f(r2);
    // lanes 0-7: q = col sum for blk = psb + lane
    if (PLANES) {
        if (lane < 8) {
            unsigned blk = psb + (unsigned)lane;
            dataout[0 * SB + blk] = q0;
            dataout[1 * SB + blk] = q1;
            dataout[2 * SB + blk] = q2;
        }
    } else {
        unsigned blk  = psb + (unsigned)(lane & 7);
        unsigned r    = blk / 101u;
        unsigned rmin = psb / 101u;
        bool low = (r == rmin);
        float A0 = low ? q0 : 0.f, A1 = low ? q1 : 0.f, A2 = low ? q2 : 0.f;
        float D0 = low ? 0.f : q0, D1 = low ? 0.f : q1, D2 = low ? 0.f : q2;
#pragma unroll
        for (int m = 1; m < 8; m <<= 1) {
            A0 += __shfl_xor(A0, m); A1 += __shfl_xor(A1, m); A2 += __shfl_xor(A2, m);
            D0 += __shfl_xor(D0, m); D1 += __shfl_xor(D1, m); D2 += __shfl_xor(D2, m);
        }
        int anyhi = __any(!low && lane < 8);
        if (lane == 0) {
            atomicAdd(&dataout[rmin * 3 + 0], A0);
            atomicAdd(&dataout[rmin * 3 + 1], A1);
            atomicAdd(&dataout[rmin * 3 + 2], A2);
            if (anyhi) {
                atomicAdd(&dataout[(rmin + 1u) * 3 + 0], D0);
                atomicAdd(&dataout[(rmin + 1u) * 3 + 1], D1);
                atomicAdd(&dataout[(rmin + 1u) * 3 + 2], D2);
            }
        }
    }
}

// Per-group activations + B-frag gather (R14 math verbatim).
__device__ __forceinline__ void act_group(const f32x4* acc, f32x2& cs, f32x2& ho, u32x4& bhv,
                                          bool htb, bool qpb) {
    f32x4 vI = htb ? acc[1] : acc[0];
    f32x4 vF = htb ? acc[3] : acc[2];
    f32x4 vG = htb ? acc[5] : acc[4];
    f32x4 vO = htb ? acc[7] : acc[6];
    f32x2 aI = qpb ? (f32x2){vI[2], vI[3]} : (f32x2){vI[0], vI[1]};
    f32x2 aF = qpb ? (f32x2){vF[2], vF[3]} : (f32x2){vF[0], vF[1]};
    f32x2 aG = qpb ? (f32x2){vG[2], vG[3]} : (f32x2){vG[0], vG[1]};
    f32x2 aO = qpb ? (f32x2){vO[2], vO[3]} : (f32x2){vO[0], vO[1]};
    f32x2 ef = {__builtin_amdgcn_exp2f(-aF.x), __builtin_amdgcn_exp2f(-aF.y)};
    f32x2 ei = {__builtin_amdgcn_exp2f(-aI.x), __builtin_amdgcn_exp2f(-aI.y)};
    f32x2 eg = {__builtin_amdgcn_exp2f(-aG.x), __builtin_amdgcn_exp2f(-aG.y)};
    f32x2 pf = ef + 1.f;
    f32x2 A  = (ei + 1.f) * (eg + 1.f);
    f32x2 num = cs * A + (1.f - eg) * pf;
    f32x2 den = pf * A;
    f32x2 rd = {__builtin_amdgcn_rcpf(den.x), __builtin_amdgcn_rcpf(den.y)};
    f32x2 cn = num * rd;
    cs = cn;
    f32x2 eo = {__builtin_amdgcn_exp2f(-aO.x), __builtin_amdgcn_exp2f(-aO.y)};
    f32x2 ec = {__builtin_amdgcn_exp2f(cn.x * N2LOG2E), __builtin_amdgcn_exp2f(cn.y * N2LOG2E)};
    f32x2 dd = (eo + 1.f) * (ec + 1.f);
    f32x2 rh = {__builtin_amdgcn_rcpf(dd.x), __builtin_amdgcn_rcpf(dd.y)};
    ho = (1.f - ec) * rh;
    // gather 4 copy-words into full B-frag: word w == cp
    unsigned own = pkh(ho.x, ho.y);
    unsigned t1 = swz4u(own);            // word cp^1
    unsigned t2 = dpp8u(own);            // word cp^2
    unsigned t3 = dpp8u(t1);             // word cp^3
    unsigned e  = qpb ? t1 : own;
    unsigned o  = qpb ? own : t1;
    unsigned e2 = qpb ? t3 : t2;
    unsigned o2 = qpb ? t2 : t3;
    bhv[0] = htb ? e2 : e;
    bhv[1] = htb ? o2 : o;
    bhv[2] = htb ? e : e2;
    bhv[3] = htb ? o : o2;
}

// Wave = 8 real rows as TWO independent 4-row groups (A: b0..3, B: b0+4..7),
// each in 4-col x 4-dup MFMA layout with 4-way activation split. Weights
// shared. Grid 2048 -> 2 waves/SIMD; 4 independent chains per SIMD. Group B's
// issue hides group A's chain stalls (and vice versa).
template<bool PLANES>
__global__ __launch_bounds__(64, 2) void lstm_kernel(
    const float* __restrict__ x,                 // [SEQ][BATCH][INP]
    const unsigned short* __restrict__ whh_g,    // [8][64][8] fp16 A-frags
    const unsigned short* __restrict__ wih_g,    // [8][64][8] fp16 A-frags (+bias k=9)
    const float* __restrict__ W_lin,             // [NOUT][HSlin]
    float* __restrict__ dataout)                 // planes [3][SB] (or accp fallback)
{
    const int lane = threadIdx.x;
    const int c4   = lane & 3;         // real col within group
    const int cp   = (lane >> 2) & 3;  // copy id
    const bool htb = (cp & 2) != 0;
    const bool qpb = (cp & 1) != 0;
    const int g    = lane >> 4;
    const int b0   = blockIdx.x * 8;
    const int bA   = b0 + c4;
    const int bB   = b0 + 4 + c4;

    half8 whh[8], xw[8];
#pragma unroll
    for (int t = 0; t < 8; ++t) {
        whh[t] = __builtin_bit_cast(half8, *reinterpret_cast<const short8*>(whh_g + (t * 64 + lane) * 8));
        xw[t]  = __builtin_bit_cast(half8, *reinterpret_cast<const short8*>(wih_g + (t * 64 + lane) * 8));
    }

    const bool g0 = (g == 0), g1 = (g == 1);
    const int u0 = (htb ? 16 : 0) + 4 * g + (qpb ? 2 : 0);   // my 2 units

    f32x2 csA = {0.f, 0.f}, csB = {0.f, 0.f};
    f32x2 hoA = {0.f, 0.f}, hoB = {0.f, 0.f};
    u32x4 bhvA = {0u,0u,0u,0u}, bhvB = {0u,0u,0u,0u};
    float xvA[9], xvB[9];
    {
        const float* xpA = x + (size_t)bA * INP;
        const float* xpB = x + (size_t)bB * INP;
#pragma unroll
        for (int i = 0; i < 9; ++i) { xvA[i] = xpA[i]; xvB[i] = xpB[i]; }
    }

    // running W_lin col: slotA = (s*BATCH + bA) mod 101; BATCH ≡ 22 (mod 101)
    unsigned rr    = (unsigned)bA / 101u;
    unsigned slotA = (unsigned)bA - rr * 101u;

    float pA0 = 0.f, pA1 = 0.f, pA2 = 0.f;
    float pB0 = 0.f, pB1 = 0.f, pB2 = 0.f;
    unsigned psb = 0;

#pragma unroll 1
    for (int s = 0; s < SEQ; ++s) {
        // (0) W_lin weights, both groups (slotB = slotA+4 mod 101)
        unsigned slotB = slotA + 4u; slotB = (slotB >= 101u) ? (slotB - 101u) : slotB;
        const float* wlA = W_lin + slotA * HID + u0;
        const float* wlB = W_lin + slotB * HID + u0;
        float2 wA0 = *(const float2*)(wlA);
        float2 wA1 = *(const float2*)(wlA + HSlin);
        float2 wA2 = *(const float2*)(wlA + 2 * HSlin);
        float2 wB0 = *(const float2*)(wlB);
        float2 wB1 = *(const float2*)(wlB + HSlin);
        float2 wB2 = *(const float2*)(wlB + 2 * HSlin);

        // (1) group A: xa pack + 16 MFMA
        const f32x4 zz = {0.f, 0.f, 0.f, 0.f};
        f32x4 accA[8], accB[8];
        {
            unsigned x01 = pkh(xvA[0], xvA[1]), x23 = pkh(xvA[2], xvA[3]);
            unsigned x45 = pkh(xvA[4], xvA[5]), x67 = pkh(xvA[6], xvA[7]);
            unsigned x81 = pkh(xvA[8], 1.0f);
            u32x4 xt;
            xt[0] = g0 ? x01 : (g1 ? x81 : 0u);
            xt[1] = g0 ? x23 : 0u;
            xt[2] = g0 ? x45 : 0u;
            xt[3] = g0 ? x67 : 0u;
            half8 xa = __builtin_bit_cast(half8, xt);
            half8 bh = __builtin_bit_cast(half8, bhvA);
#pragma unroll
            for (int t = 0; t < 8; ++t) {
                accA[t] = __builtin_amdgcn_mfma_f32_16x16x32_f16(xw[t], xa, zz, 0, 0, 0);
                accA[t] = __builtin_amdgcn_mfma_f32_16x16x32_f16(whh[t], bh, accA[t], 0, 0, 0);
            }
        }
        // (2) group B: xa pack + 16 MFMA (issues under A's latency)
        {
            unsigned x01 = pkh(xvB[0], xvB[1]), x23 = pkh(xvB[2], xvB[3]);
            unsigned x45 = pkh(xvB[4], xvB[5]), x67 = pkh(xvB[6], xvB[7]);
            unsigned x81 = pkh(xvB[8], 1.0f);
            u32x4 xt;
            xt[0] = g0 ? x01 : (g1 ? x81 : 0u);
            xt[1] = g0 ? x23 : 0u;
            xt[2] = g0 ? x45 : 0u;
            xt[3] = g0 ? x67 : 0u;
            half8 xa = __builtin_bit_cast(half8, xt);
            half8 bh = __builtin_bit_cast(half8, bhvB);
#pragma unroll
            for (int t = 0; t < 8; ++t) {
                accB[t] = __builtin_amdgcn_mfma_f32_16x16x32_f16(xw[t], xa, zz, 0, 0, 0);
                accB[t] = __builtin_amdgcn_mfma_f32_16x16x32_f16(whh[t], bh, accB[t], 0, 0, 0);
            }
        }
        // (3) previous step's merged emit — hides under MFMA latency
        if (s > 0) emit_prev2<PLANES>(pA0, pA1, pA2, pB0, pB1, pB2, psb, dataout, lane);

        // (4) prefetch next step's x (both groups)
        float xnA[9], xnB[9];
        if (s < SEQ - 1) {
            const float* xpA = x + ((size_t)(s + 1) * BATCH + bA) * INP;
            const float* xpB = x + ((size_t)(s + 1) * BATCH + bB) * INP;
#pragma unroll
            for (int i = 0; i < 9; ++i) { xnA[i] = xpA[i]; xnB[i] = xpB[i]; }
        }

        // (5) activations + gather, group A then B (independent chains interleave)
        act_group(accA, csA, hoA, bhvA, htb, qpb);
        act_group(accB, csB, hoB, bhvB, htb, qpb);

        if (s < SEQ - 1) {
#pragma unroll
            for (int i = 0; i < 9; ++i) { xvA[i] = xnA[i]; xvB[i] = xnB[i]; }
        }

        // (6) W_lin partials — my 2 units, both groups
        pA0 = wA0.x * hoA.x + wA0.y * hoA.y;
        pA1 = wA1.x * hoA.x + wA1.y * hoA.y;
        pA2 = wA2.x * hoA.x + wA2.y * hoA.y;
        pB0 = wB0.x * hoB.x + wB0.y * hoB.y;
        pB1 = wB1.x * hoB.x + wB1.y * hoB.y;
        pB2 = wB2.x * hoB.x + wB2.y * hoB.y;
        psb = ((unsigned)s << 14) + (unsigned)b0;            // s*BATCH + b0

        slotA += 22u;                                        // (+BATCH) mod 101
        slotA = (slotA >= 101u) ? (slotA - 101u) : slotA;
    }
    // epilogue: emit for s = SEQ-1
    emit_prev2<PLANES>(pA0, pA1, pA2, pB0, pB1, pB2, psb, dataout, lane);
}

// Plane path: one wave per output row sums its 101 contiguous cols.
__global__ void finalize_planes(const float* __restrict__ planes, const float* __restrict__ b_lin,
                                float* __restrict__ out) {
    int wid = (blockIdx.x * blockDim.x + threadIdx.x) >> 6;   // row 0..16383
    int l   = threadIdx.x & 63;
    float v[3];
#pragma unroll
    for (int o = 0; o < 3; ++o) {
        const float* p = planes + (size_t)o * SB + (size_t)wid * 101;
        float t = p[l] + ((l < 37) ? p[l + 64] : 0.f);
#pragma unroll
        for (int m = 1; m < 64; m <<= 1) t += __shfl_xor(t, m);
        v[o] = t;
    }
    if (l == 0) {
        out[wid * 3 + 0] = v[0] + b_lin[0];
        out[wid * 3 + 1] = v[1] + b_lin[1];
        out[wid * 3 + 2] = v[2] + b_lin[2];
    }
}

__global__ void finalize_acc(const float* __restrict__ acc, const float* __restrict__ b_lin,
                             float* __restrict__ out) {
    int i = blockIdx.x * blockDim.x + threadIdx.x;
    if (i < BATCH * NOUT) {
        int r = i / 3;
        int o = i - r * 3;
        out[i] = acc[i] + b_lin[o];
    }
}

extern "C" void kernel_launch(void* const* d_in, const int* in_sizes, int n_in,
                              void* d_out, int out_size, void* d_ws, size_t ws_size,
                              hipStream_t stream) {
    const float* x     = (const float*)d_in[0];
    const float* W_ih  = (const float*)d_in[1];
    const float* W_hh  = (const float*)d_in[2];
    const float* b_ih  = (const float*)d_in[3];
    const float* b_hh  = (const float*)d_in[4];
    const float* W_lin = (const float*)d_in[5];
    const float* b_lin = (const float*)d_in[6];
    float* out = (float*)d_out;

    // ws: whh16[4096]u16 | wih16[4096]u16 | (pad) | data...
    unsigned short* whh16 = (unsigned short*)d_ws;
    unsigned short* wih16 = whh16 + 4096;
    float* data  = (float*)((char*)d_ws + 25600);

    size_t need_planes = 25600 + (size_t)3 * SB * sizeof(float);
    bool planes = ws_size >= need_planes;

    hipLaunchKernelGGL(prep_kernel, dim3(1), dim3(512), 0, stream,
                       W_ih, W_hh, b_ih, b_hh, whh16, wih16);
    if (planes) {
        hipLaunchKernelGGL((lstm_kernel<true>), dim3(BATCH / 8), dim3(64), 0, stream,
                           x, whh16, wih16, W_lin, data);
        hipLaunchKernelGGL(finalize_planes, dim3(BATCH / 4), dim3(256), 0, stream,
                           data, b_lin, out);
    } else {
        hipMemsetAsync(data, 0, 49160 * sizeof(float), stream);
        hipLaunchKernelGGL((lstm_kernel<false>), dim3(BATCH / 8), dim3(64), 0, stream,
                           x, whh16, wih16, W_lin, data);
        hipLaunchKernelGGL(finalize_acc, dim3((BATCH * NOUT + 255) / 256), dim3(256), 0, stream,
                           data, b_lin, out);
    }
}

// Round 16
// 115.428 us; speedup vs baseline: 4.5313x; 4.5313x over previous
//
#include <hip/hip_runtime.h>
#include <hip/hip_bf16.h>

#define SEQ   101
#define BATCH 16384
#define INP   9
#define HID   32
#define NOUT  3
#define HSlin 3232          // HID*SEQ
#define SB    (SEQ * BATCH) // flattened (s,b) cols

typedef __attribute__((ext_vector_type(8))) _Float16 half8;   // 8 fp16 (4 VGPRs)
typedef __attribute__((ext_vector_type(8))) short short8;
typedef __attribute__((ext_vector_type(4))) float f32x4;      // MFMA C/D
typedef __attribute__((ext_vector_type(2))) float f32x2;      // v_pk_* pairs
typedef __attribute__((ext_vector_type(4))) unsigned u32x4;

#define LOG2E   1.4426950408889634f
#define N2LOG2E (-2.8853900817779268f)

// pack two f32 -> half2 in one v_cvt_pkrtz_f16_f32
__device__ __forceinline__ unsigned pkh(float a, float b) {
    return __builtin_bit_cast(unsigned, __builtin_amdgcn_cvt_pkrtz(a, b));
}
// DPP row_ror:8 — within each 16-lane row, lane i <-> lane i^8
__device__ __forceinline__ unsigned dpp8u(unsigned v) {
    return (unsigned)__builtin_amdgcn_mov_dpp((int)v, 0x128, 0xF, 0xF, true);
}
__device__ __forceinline__ float dpp8f(float v) {
    return __int_as_float(__builtin_amdgcn_mov_dpp(__float_as_int(v), 0x128, 0xF, 0xF, true));
}

// Swapped-operand scheme: gates^T = W * [x|h]^T, fp16 single-pass (R11 base).
// Weights pre-scaled by log2e (i,f,o) / 2*log2e (g) so activations use raw exp2.
// k-permutation for h: pi(8g+j) = 4g + (j&3) + 16*(j>>2).
// x map: k=0..8 -> W_ih column k; k>=9 -> 0.
__global__ void prep_kernel(const float* __restrict__ W_ih, const float* __restrict__ W_hh,
                            const float* __restrict__ b_ih, const float* __restrict__ b_hh,
                            unsigned short* __restrict__ whh16, unsigned short* __restrict__ wih16,
                            float* __restrict__ biasc) {
    int tid = threadIdx.x;            // 0..511 : t = tid>>6, l = tid&63
    int l   = tid & 63;
    int t   = tid >> 6;
    int row = l & 15;                 // gate-in-tile
    int g   = l >> 4;
    int gate = 16 * t + row;
    float sc = ((gate >> 5) == 2) ? (2.f * LOG2E) : LOG2E;    // g-gate: tanh needs e^{-2g}
    for (int j = 0; j < 8; ++j) {
        int u = 4 * g + (j & 3) + 16 * (j >> 2);     // pi(8g+j)
        _Float16 wh = (_Float16)(W_hh[gate * HID + u] * sc);
        whh16[tid * 8 + j] = __builtin_bit_cast(unsigned short, wh);
        int k = 8 * g + j;
        _Float16 wi = (_Float16)((k < INP) ? (W_ih[gate * INP + k] * sc) : 0.f);
        wih16[tid * 8 + j] = __builtin_bit_cast(unsigned short, wi);
    }
    if (tid < 4 * HID) {
        float bs = ((tid >> 5) == 2) ? (2.f * LOG2E) : LOG2E;
        biasc[tid] = (b_ih[tid] + b_hh[tid]) * bs;
    }
}

// Emit staged W_lin partials (base psb = s*BATCH + b0). xor8 merge via DPP;
// xor16/32 via shuffle (off critical path).
template<bool PLANES>
__device__ __forceinline__ void emit_prev(float p0, float p1, float p2,
                                          unsigned psb, float* __restrict__ dataout,
                                          int lane, int cr) {
    p0 += dpp8f(p0);          p1 += dpp8f(p1);          p2 += dpp8f(p2);
    p0 += __shfl_xor(p0, 16); p1 += __shfl_xor(p1, 16); p2 += __shfl_xor(p2, 16);
    p0 += __shfl_xor(p0, 32); p1 += __shfl_xor(p1, 32); p2 += __shfl_xor(p2, 32);
    if (PLANES) {
        if (lane < 8) {
            unsigned blk = psb + (unsigned)lane;
            dataout[0 * SB + blk] = p0;
            dataout[1 * SB + blk] = p1;
            dataout[2 * SB + blk] = p2;
        }
    } else {
        // fallback: <=2 output rows across the 8 cols; butterfly + lane-0 atomics
        unsigned blk  = psb + (unsigned)cr;
        unsigned r    = blk / 101u;
        unsigned rmin = psb / 101u;
        bool low = (r == rmin);
        float a0 = low ? p0 : 0.f, a1 = low ? p1 : 0.f, a2 = low ? p2 : 0.f;
        float d0 = low ? 0.f : p0, d1 = low ? 0.f : p1, d2 = low ? 0.f : p2;
#pragma unroll
        for (int m = 1; m < 8; m <<= 1) {
            a0 += __shfl_xor(a0, m); a1 += __shfl_xor(a1, m); a2 += __shfl_xor(a2, m);
            d0 += __shfl_xor(d0, m); d1 += __shfl_xor(d1, m); d2 += __shfl_xor(d2, m);
        }
        int anyhi = __any(!low && lane < 8);
        if (lane == 0) {
            atomicAdd(&dataout[rmin * 3 + 0], a0);
            atomicAdd(&dataout[rmin * 3 + 1], a1);
            atomicAdd(&dataout[rmin * 3 + 2], a2);
            if (anyhi) {
                atomicAdd(&dataout[(rmin + 1u) * 3 + 0], d0);
                atomicAdd(&dataout[(rmin + 1u) * 3 + 1], d1);
                atomicAdd(&dataout[(rmin + 1u) * 3 + 2], d2);
            }
        }
    }
}

// One INDEPENDENT wave per 8 batch rows (cols 8-15 duplicate 0-7), no barriers,
// 2 waves/SIMD (R11 structure — best measured). NEW: s_setprio(1) around the
// MFMA cluster (T5 — independent-wave regime), running slot counter, psb shift.
template<bool PLANES>
__global__ __launch_bounds__(64, 2) void lstm_kernel(
    const float* __restrict__ x,                 // [SEQ][BATCH][INP]
    const unsigned short* __restrict__ whh_g,    // [8][64][8] fp16 A-frags
    const unsigned short* __restrict__ wih_g,    // [8][64][8] fp16 A-frags
    const float* __restrict__ biasc,             // [4H] (pre-scaled)
    const float* __restrict__ W_lin,             // [NOUT][HSlin]
    float* __restrict__ dataout)                 // planes [3][SB] (or accp fallback)
{
    const int lane = threadIdx.x;
    const int c    = lane & 15;        // MFMA batch col
    const int cr   = c & 7;            // real batch col (8-15 duplicate 0-7)
    const bool hi8 = (lane & 8) != 0;  // this lane owns half1 (units 16+4g+q)
    const int g    = lane >> 4;
    const int b0   = blockIdx.x * 8;
    const int b    = b0 + cr;

    // Static A-fragments + per-lane bias quads (live across all steps)
    half8 whh[8], xw[8];
    f32x4 biasv[8];
#pragma unroll
    for (int t = 0; t < 8; ++t) {
        whh[t] = __builtin_bit_cast(half8, *reinterpret_cast<const short8*>(whh_g + (t * 64 + lane) * 8));
        xw[t]  = __builtin_bit_cast(half8, *reinterpret_cast<const short8*>(wih_g + (t * 64 + lane) * 8));
        biasv[t] = *reinterpret_cast<const f32x4*>(biasc + 16 * t + 4 * g);
    }

    const bool g0 = (g == 0), g1 = (g == 1);

    f32x2 cs[2] = {{0.f, 0.f}, {0.f, 0.f}};      // c-state: my half's 4 units
    f32x2 ho[2] = {{0.f, 0.f}, {0.f, 0.f}};      // my half's h (for W_lin dot)
    u32x4 bhv = {0u, 0u, 0u, 0u};                // packed fp16 h B-frag (persistent)
    float xv[9];
    {
        const float* xp = x + (size_t)b * INP;           // s = 0
#pragma unroll
        for (int i = 0; i < 9; ++i) xv[i] = xp[i];
    }

    // running W_lin column: slot = (s*BATCH + b) mod 101; BATCH ≡ 22 (mod 101)
    unsigned rr   = (unsigned)b / 101u;
    unsigned slot = (unsigned)b - rr * 101u;

    float pp0 = 0.f, pp1 = 0.f, pp2 = 0.f;               // staged W_lin partials
    unsigned psb = 0;

#pragma unroll 1
    for (int s = 0; s < SEQ; ++s) {
        // (0) this step's W_lin weights — only my half's 4 columns per plane
        const float* wl = W_lin + slot * HID + 4 * g + (hi8 ? 16 : 0);
        float4 w0 = *(const float4*)(wl);
        float4 w1 = *(const float4*)(wl + HSlin);
        float4 w2 = *(const float4*)(wl + 2 * HSlin);

        // (1) fp16 x B-fragment: g=0 supplies x0..x7 (k=0..7), g=1 supplies x8
        short8 xa;
        {
            unsigned x01 = pkh(xv[0], xv[1]), x23 = pkh(xv[2], xv[3]);
            unsigned x45 = pkh(xv[4], xv[5]), x67 = pkh(xv[6], xv[7]);
            unsigned x8z = pkh(xv[8], 0.f);
            u32x4 xt;
            xt[0] = g0 ? x01 : (g1 ? x8z : 0u);
            xt[1] = g0 ? x23 : 0u;
            xt[2] = g0 ? x45 : 0u;
            xt[3] = g0 ? x67 : 0u;
            xa = __builtin_bit_cast(short8, xt);
        }
        // (2) h B-fragment: already packed+exchanged (persistent state)
        half8 bh = __builtin_bit_cast(half8, bhv);

        // (3) gates^T: 8 tiles x 2 MFMA (fp16, fp32-accum), setprio-wrapped
        f32x4 acc[8];
        __builtin_amdgcn_s_setprio(1);
#pragma unroll
        for (int t = 0; t < 8; ++t) {
            acc[t] = __builtin_amdgcn_mfma_f32_16x16x32_f16(xw[t], __builtin_bit_cast(half8, xa), biasv[t], 0, 0, 0);
            acc[t] = __builtin_amdgcn_mfma_f32_16x16x32_f16(whh[t], bh, acc[t], 0, 0, 0);
        }
        __builtin_amdgcn_s_setprio(0);
        // (4) previous step's reduce + stores — hides under MFMA latency
        if (s > 0) emit_prev<PLANES>(pp0, pp1, pp2, psb, dataout, lane, cr);

        // (5) prefetch next step's x
        float xn[9];
        if (s < SEQ - 1) {
            const float* xpn = x + ((size_t)(s + 1) * BATCH + b) * INP;
#pragma unroll
            for (int i = 0; i < 9; ++i) xn[i] = xpn[i];
        }

        // (6) activations for MY half (4 units as 2 float2 pairs, v_pk math).
        //     c' = [c*(1+ei)(1+eg) + (1-eg)(1+ef)] / [(1+ef)(1+ei)(1+eg)]
        //     h  = (1-ec) / ((1+eo)(1+ec)),  ec = exp2(c' * -2log2e)
        f32x4 aI = hi8 ? acc[1] : acc[0];
        f32x4 aF = hi8 ? acc[3] : acc[2];
        f32x4 aG = hi8 ? acc[5] : acc[4];
        f32x4 aO = hi8 ? acc[7] : acc[6];
#pragma unroll
        for (int p = 0; p < 2; ++p) {
            f32x2 ef = {__builtin_amdgcn_exp2f(-aF[2*p]), __builtin_amdgcn_exp2f(-aF[2*p+1])};
            f32x2 ei = {__builtin_amdgcn_exp2f(-aI[2*p]), __builtin_amdgcn_exp2f(-aI[2*p+1])};
            f32x2 eg = {__builtin_amdgcn_exp2f(-aG[2*p]), __builtin_amdgcn_exp2f(-aG[2*p+1])};
            f32x2 pf = ef + 1.f;
            f32x2 A  = (ei + 1.f) * (eg + 1.f);
            f32x2 num = cs[p] * A + (1.f - eg) * pf;
            f32x2 den = pf * A;
            f32x2 rd = {__builtin_amdgcn_rcpf(den.x), __builtin_amdgcn_rcpf(den.y)};
            f32x2 cn = num * rd;
            cs[p] = cn;
            f32x2 eo = {__builtin_amdgcn_exp2f(-aO[2*p]), __builtin_amdgcn_exp2f(-aO[2*p+1])};
            f32x2 ec = {__builtin_amdgcn_exp2f(cn.x * N2LOG2E), __builtin_amdgcn_exp2f(cn.y * N2LOG2E)};
            f32x2 dd = (eo + 1.f) * (ec + 1.f);
            f32x2 rh = {__builtin_amdgcn_rcpf(dd.x), __builtin_amdgcn_rcpf(dd.y)};
            ho[p] = (1.f - ec) * rh;
        }
        // (6b) pack own half to fp16, DPP-exchange with twin, order into B-frag
        {
            unsigned oh01 = pkh(ho[0].x, ho[0].y);
            unsigned oh23 = pkh(ho[1].x, ho[1].y);
            unsigned th01 = dpp8u(oh01), th23 = dpp8u(oh23);
            bhv[0] = hi8 ? th01 : oh01;  bhv[1] = hi8 ? th23 : oh23;
            bhv[2] = hi8 ? oh01 : th01;  bhv[3] = hi8 ? oh23 : th23;
        }
        if (s < SEQ - 1) {
#pragma unroll
            for (int i = 0; i < 9; ++i) xv[i] = xn[i];
        }

        // (7) this step's W_lin partial — my half's 4 units only
        pp0 = w0.x * ho[0].x + w0.y * ho[0].y + w0.z * ho[1].x + w0.w * ho[1].y;
        pp1 = w1.x * ho[0].x + w1.y * ho[0].y + w1.z * ho[1].x + w1.w * ho[1].y;
        pp2 = w2.x * ho[0].x + w2.y * ho[0].y + w2.z * ho[1].x + w2.w * ho[1].y;
        psb = ((unsigned)s << 14) + (unsigned)b0;            // s*BATCH + b0

        slot += 22u;                                         // (+BATCH) mod 101
        slot = (slot >= 101u) ? (slot - 101u) : slot;
    }
    // epilogue: emit for s = SEQ-1
    emit_prev<PLANES>(pp0, pp1, pp2, psb, dataout, lane, cr);
}

// Plane path: one wave per output row sums its 101 contiguous cols.
__global__ void finalize_planes(const float* __restrict__ planes, const float* __restrict__ b_lin,
                                float* __restrict__ out) {
    int wid = (blockIdx.x * blockDim.x + threadIdx.x) >> 6;   // row 0..16383
    int l   = threadIdx.x & 63;
    float v[3];
#pragma unroll
    for (int o = 0; o < 3; ++o) {
        const float* p = planes + (size_t)o * SB + (size_t)wid * 101;
        float t = p[l] + ((l < 37) ? p[l + 64] : 0.f);
#pragma unroll
        for (int m = 1; m < 64; m <<= 1) t += __shfl_xor(t, m);
        v[o] = t;
    }
    if (l == 0) {
        out[wid * 3 + 0] = v[0] + b_lin[0];
        out[wid * 3 + 1] = v[1] + b_lin[1];
        out[wid * 3 + 2] = v[2] + b_lin[2];
    }
}

__global__ void finalize_acc(const float* __restrict__ acc, const float* __restrict__ b_lin,
                             float* __restrict__ out) {
    int i = blockIdx.x * blockDim.x + threadIdx.x;
    if (i < BATCH * NOUT) {
        int r = i / 3;
        int o = i - r * 3;
        out[i] = acc[i] + b_lin[o];
    }
}

extern "C" void kernel_launch(void* const* d_in, const int* in_sizes, int n_in,
                              void* d_out, int out_size, void* d_ws, size_t ws_size,
                              hipStream_t stream) {
    const float* x     = (const float*)d_in[0];
    const float* W_ih  = (const float*)d_in[1];
    const float* W_hh  = (const float*)d_in[2];
    const float* b_ih  = (const float*)d_in[3];
    const float* b_hh  = (const float*)d_in[4];
    const float* W_lin = (const float*)d_in[5];
    const float* b_lin = (const float*)d_in[6];
    float* out = (float*)d_out;

    // ws: whh16[4096]u16 | wih16[4096]u16 | biasc[128]f32 | (pad) | data...
    unsigned short* whh16 = (unsigned short*)d_ws;
    unsigned short* wih16 = whh16 + 4096;
    float* biasc = (float*)(wih16 + 4096);
    float* data  = (float*)((char*)d_ws + 25600);

    size_t need_planes = 25600 + (size_t)3 * SB * sizeof(float);
    bool planes = ws_size >= need_planes;

    hipLaunchKernelGGL(prep_kernel, dim3(1), dim3(512), 0, stream,
                       W_ih, W_hh, b_ih, b_hh, whh16, wih16, biasc);
    if (planes) {
        hipLaunchKernelGGL((lstm_kernel<true>), dim3(BATCH / 8), dim3(64), 0, stream,
                           x, whh16, wih16, biasc, W_lin, data);
        hipLaunchKernelGGL(finalize_planes, dim3(BATCH / 4), dim3(256), 0, stream,
                           data, b_lin, out);
    } else {
        hipMemsetAsync(data, 0, 49160 * sizeof(float), stream);
        hipLaunchKernelGGL((lstm_kernel<false>), dim3(BATCH / 8), dim3(64), 0, stream,
                           x, whh16, wih16, biasc, W_lin, data);
        hipLaunchKernelGGL(finalize_acc, dim3((BATCH * NOUT + 255) / 256), dim3(256), 0, stream,
                           data, b_lin, out);
    }
}